// Round 3
// baseline (262.035 us; speedup 1.0000x reference)
//
#include <hip/hip_runtime.h>
#include <math.h>

// Problem constants (from reference setup_inputs).
constexpr int B_ = 2048;
constexpr int C_ = 9605;
constexpr int L_ = 8;
constexpr int TOPK_ = 16;
constexpr int CAP_ = 512;       // LDS candidate capacity (expected ~219 per row)
constexpr int NSLOT_ = 8;       // per-thread candidate register slots
constexpr float T0_ = 2.0f;     // candidate prefilter threshold (16th largest ~2.95)
constexpr int QW_ = 2404;       // packed-code quads per rotation (>= max n4 + 1)

__device__ __forceinline__ float sigm(float v) { return 1.0f / (1.0f + expf(-v)); }

// our_rank_loss: d = x2 - x1 + margin; s = sigmoid(5d); 2s when violated (d>0)
__device__ __forceinline__ float rank_loss(float x1, float x2) {
  float d = x2 - x1 + 0.05f;
  float s = 1.0f / (1.0f + expf(-5.0f * d));
  return (d > 0.0f) ? 2.0f * s : s;
}

// Order-preserving float->uint key (ascending) and inverse.
__device__ __forceinline__ unsigned int fkey(float v) {
  unsigned int u = __float_as_uint(v);
  return u ^ ((u & 0x80000000u) ? 0xFFFFFFFFu : 0x80000000u);
}
__device__ __forceinline__ float fkeyinv(unsigned int k) {
  unsigned int u = (k & 0x80000000u) ? (k ^ 0x80000000u) : ~k;
  return __uint_as_float(u);
}

// Kernel 0a: group_mask [L, C] int32 (bool promoted) -> per-class code byte.
__global__ void build_code_kernel(const int* __restrict__ mask,
                                  unsigned char* __restrict__ code) {
  int c = blockIdx.x * 256 + threadIdx.x;
  if (c >= C_) return;
  unsigned char cd = 0xFF;
#pragma unroll
  for (int l = L_ - 1; l >= 0; --l)
    if (mask[l * C_ + c] != 0) cd = (unsigned char)l;
  code[c] = cd;
}

// Kernel 0b: rotated packed code tables. codeq[r][k] packs codes of classes
// (r+4k .. r+4k+3) so a row whose interior starts at class `lead` reads one
// aligned dword per quad (codeq[lead][k]).
__global__ void pack_code_kernel(const unsigned char* __restrict__ code,
                                 unsigned int* __restrict__ codeq) {
  int k = blockIdx.x * 256 + threadIdx.x;
  int r = blockIdx.y;
  if (k >= QW_) return;
  unsigned int v = 0u;
#pragma unroll
  for (int e = 0; e < 4; ++e) {
    int c = r + 4 * k + e;
    unsigned int byte = (c < C_) ? (unsigned int)code[c] : 0xFFu;
    v |= byte << (8 * e);
  }
  codeq[r * QW_ + k] = v;
}

// Kernel 1: one block per row. All-register hot loop (no LDS, no divergent
// branches): group maxima, gt bits, candidate slots per thread; then wave
// shuffle reduction, LDS candidate compaction, exact 16th-largest, epilogue.
__global__ void __launch_bounds__(256) row_loss_kernel(
    const float* __restrict__ x, const float* __restrict__ y,
    const float* __restrict__ yn, const unsigned char* __restrict__ code,
    const unsigned int* __restrict__ codeq, float* __restrict__ loss) {
  __shared__ float cand[CAP_];
  __shared__ int cand_cnt;
  __shared__ int s_of;                 // any-thread candidate-slot overflow
  __shared__ float wgm[4][L_];
  __shared__ unsigned int wgt[4], wgn[4];
  __shared__ float s_x16;
  __shared__ int s_red;

  const int t = threadIdx.x;
  const int b = blockIdx.x;
  const float* xr = x + (size_t)b * C_;
  const float* yr = y + (size_t)b * C_;
  const float* ynr = yn + (size_t)b * C_;

  if (t == 0) { cand_cnt = 0; s_of = 0; }

  // Per-thread accumulators (registers only).
  float gm[L_];
#pragma unroll
  for (int l = 0; l < L_; ++l) gm[l] = -INFINITY;
  unsigned int gtb = 0u, gnb = 0u;
  float cnd[NSLOT_];
  int cc = 0;
#pragma unroll
  for (int k = 0; k < NSLOT_; ++k) cnd[k] = -INFINITY;

  auto proc = [&](float xv, float yv, float nv, int cd) {
#pragma unroll
    for (int l = 0; l < L_; ++l)
      if (cd == l) gm[l] = fmaxf(gm[l], xv);          // predicated max, 3 VALU
    unsigned int mb = (cd < L_) ? (1u << (cd & 7)) : 0u;
    gtb |= (yv > 0.0f) ? mb : 0u;
    gnb |= (nv > 0.0f) ? mb : 0u;
    int cci = (xv > T0_) ? cc : NSLOT_;               // NSLOT_ = "no insert"
#pragma unroll
    for (int k = 0; k < NSLOT_; ++k)
      if (cci == k) cnd[k] = xv;                      // predicated slot write
    cc += (xv > T0_) ? 1 : 0;
  };

  // Interior: aligned float4 over the row body. Row start offset within its
  // first quad: r = (b*C) % 4 = b % 4 (since C % 4 == 1).
  const int r = b & 3;
  const int lead = (4 - r) & 3;
  const int n4 = (C_ - lead) >> 2;
  const float4* x4 = reinterpret_cast<const float4*>(x) + (((size_t)b * C_ + lead) >> 2);
  const float4* y4 = reinterpret_cast<const float4*>(y) + (((size_t)b * C_ + lead) >> 2);
  const float4* v4 = reinterpret_cast<const float4*>(yn) + (((size_t)b * C_ + lead) >> 2);
  const unsigned int* cq = codeq + lead * QW_;

  for (int k = t; k < n4; k += 256) {
    float4 xv = x4[k];
    float4 yv = y4[k];
    float4 nv = v4[k];
    unsigned int cqk = cq[k];
    proc(xv.x, yv.x, nv.x, (int)(cqk & 0xFF));
    proc(xv.y, yv.y, nv.y, (int)((cqk >> 8) & 0xFF));
    proc(xv.z, yv.z, nv.z, (int)((cqk >> 16) & 0xFF));
    proc(xv.w, yv.w, nv.w, (int)((cqk >> 24) & 0xFF));
  }
  // Head (classes [0,lead)) and tail (classes [lead+4*n4, C)): <= 6 scalars.
  if (t < lead) proc(xr[t], yr[t], ynr[t], (int)code[t]);
  const int tstart = lead + (n4 << 2);
  if (t >= 4 && t < 4 + (C_ - tstart)) {
    int c = tstart + (t - 4);
    proc(xr[c], yr[c], ynr[c], (int)code[c]);
  }

  // Wave-level reduction (width 64).
#pragma unroll
  for (int off = 32; off > 0; off >>= 1) {
#pragma unroll
    for (int l = 0; l < L_; ++l) gm[l] = fmaxf(gm[l], __shfl_xor(gm[l], off, 64));
    gtb |= (unsigned int)__shfl_xor((int)gtb, off, 64);
    gnb |= (unsigned int)__shfl_xor((int)gnb, off, 64);
  }

  __syncthreads();  // cand_cnt/s_of init visible before flush

  // Candidate flush: one atomicAdd per thread with candidates, <=8 writes.
  int nw = (cc < NSLOT_) ? cc : NSLOT_;
  if (nw > 0) {
    int pos = atomicAdd(&cand_cnt, nw);
#pragma unroll
    for (int k = 0; k < NSLOT_; ++k)
      if (k < nw && pos + k < CAP_) cand[pos + k] = cnd[k];
  }
  if (cc > NSLOT_) atomicOr(&s_of, 1);

  if ((t & 63) == 0) {
    int w = t >> 6;
#pragma unroll
    for (int l = 0; l < L_; ++l) wgm[w][l] = gm[l];
    wgt[w] = gtb;
    wgn[w] = gnb;
  }
  __syncthreads();

  const int cnt = cand_cnt;
  const bool mainp = (cnt >= TOPK_) && (cnt <= CAP_) && (s_of == 0);
  if (mainp) {
    if (t < 64) {  // wave 0: binary search on ordered keys, candidates in regs
      unsigned int ku[CAP_ / 64];
#pragma unroll
      for (int k = 0; k < CAP_ / 64; ++k) {
        int idx = t + (k << 6);
        ku[k] = (idx < cnt) ? fkey(cand[idx]) : 0u;
      }
      unsigned int lo = 0u, hi = 0xFFFFFFFFu;
      for (int it = 0; it < 32 && lo < hi; ++it) {
        unsigned int mid = lo + ((hi - lo) >> 1) + 1u;
        int c16 = 0;
#pragma unroll
        for (int k = 0; k < CAP_ / 64; ++k) c16 += (ku[k] >= mid) ? 1 : 0;
#pragma unroll
        for (int off = 32; off > 0; off >>= 1) c16 += __shfl_xor(c16, off, 64);
        if (c16 >= TOPK_) lo = mid; else hi = mid - 1u;
      }
      if (t == 0) s_x16 = fkeyinv(lo);
    }
  } else {
    // Fallback (statistically never): exact block-wide counting binary search
    // re-reading the row. Block-uniform control flow -> barriers safe.
    unsigned int lo = 0u, hi = 0xFFFFFFFFu;
    for (int it = 0; it < 32; ++it) {
      if (lo >= hi) break;
      unsigned int mid = lo + ((hi - lo) >> 1) + 1u;
      if (t == 0) s_red = 0;
      __syncthreads();
      int cl = 0;
      for (int c = t; c < C_; c += 256) cl += (fkey(xr[c]) >= mid) ? 1 : 0;
      atomicAdd(&s_red, cl);
      __syncthreads();
      int total = s_red;
      __syncthreads();
      if (total >= TOPK_) lo = mid; else hi = mid - 1u;
    }
    if (t == 0) s_x16 = fkeyinv(lo);
  }
  __syncthreads();

  // Epilogue: combine 4 wave partials, 9 sigmoids + 10 rank-losses.
  if (t == 0) {
    float thres = fmaxf(sigm(s_x16), 0.3f);
    unsigned int gtbf = wgt[0] | wgt[1] | wgt[2] | wgt[3];
    unsigned int gnbf = wgn[0] | wgn[1] | wgn[2] | wgn[3];
    float caseB = 0.0f, unio = -INFINITY, negmax = -INFINITY;
#pragma unroll
    for (int l = 0; l < L_; ++l) {
      float gx = fmaxf(fmaxf(wgm[0][l], wgm[1][l]), fmaxf(wgm[2][l], wgm[3][l]));
      float g = sigm(gx);
      unio = fmaxf(unio, g);
      caseB += ((gtbf >> l) & 1u) ? rank_loss(g, thres) : rank_loss(thres, g);
      if ((gnbf >> l) & 1u) negmax = fmaxf(negmax, g);
    }
    float negscore = (gnbf != 0u) ? negmax : 0.0f;
    float caseA = 0.5f * rank_loss(thres, unio) + 0.5f * rank_loss(thres, negscore);
    loss[b] = (gtbf != 0u) ? caseB : caseA;
  }
}

// Kernel 2: deterministic mean of the 2048 per-row losses.
__global__ void mean_kernel(const float* __restrict__ loss, float* __restrict__ out) {
  const int t = threadIdx.x;
  float s = 0.0f;
  for (int i = t; i < B_; i += 256) s += loss[i];
#pragma unroll
  for (int off = 32; off > 0; off >>= 1) s += __shfl_xor(s, off, 64);
  __shared__ float part[4];
  if ((t & 63) == 0) part[t >> 6] = s;
  __syncthreads();
  if (t == 0) out[0] = (part[0] + part[1] + part[2] + part[3]) * (1.0f / (float)B_);
}

extern "C" void kernel_launch(void* const* d_in, const int* in_sizes, int n_in,
                              void* d_out, int out_size, void* d_ws, size_t ws_size,
                              hipStream_t stream) {
  const float* x = (const float*)d_in[0];
  const float* y = (const float*)d_in[1];
  const float* yn = (const float*)d_in[2];
  const int* mask = (const int*)d_in[3];  // bool promoted to int32 by harness

  float* loss = (float*)d_ws;                                        // 8 KB
  unsigned char* code = (unsigned char*)d_ws + 8192;                 // 9605 B
  unsigned int* codeq = (unsigned int*)((char*)d_ws + 8192 + 9612);  // 4*QW_ dwords

  hipLaunchKernelGGL(build_code_kernel, dim3((C_ + 255) / 256), dim3(256), 0, stream,
                     mask, code);
  hipLaunchKernelGGL(pack_code_kernel, dim3((QW_ + 255) / 256, 4), dim3(256), 0, stream,
                     code, codeq);
  hipLaunchKernelGGL(row_loss_kernel, dim3(B_), dim3(256), 0, stream,
                     x, y, yn, code, codeq, loss);
  hipLaunchKernelGGL(mean_kernel, dim3(1), dim3(256), 0, stream,
                     loss, (float*)d_out);
}